// Round 4
// baseline (2336.358 us; speedup 1.0000x reference)
//
#include <hip/hip_runtime.h>

#define HW 1024
#define NIMG 32
#define IMGPX ((size_t)HW * HW)
#define NELEM (NIMG * IMGPX)

// ---- float <-> order-preserving unsigned (for atomic min/max) ----
__device__ __forceinline__ unsigned f2s(float f) {
    unsigned u = __float_as_uint(f);
    return (u & 0x80000000u) ? ~u : (u | 0x80000000u);
}
__device__ __forceinline__ float s2f(unsigned u) {
    return __uint_as_float((u & 0x80000000u) ? (u & 0x7fffffffu) : ~u);
}

__global__ void mm_init(unsigned* mm) {
    mm[0] = 0xFFFFFFFFu;  // running min (sortable domain)
    mm[1] = 0u;           // running max
}

__global__ __launch_bounds__(256) void mm_reduce(const float4* __restrict__ x,
                                                 unsigned* mm, int n4) {
    const int tid = threadIdx.x;
    int gid = blockIdx.x * blockDim.x + tid;
    const int stride = gridDim.x * blockDim.x;
    float vmin = 3.4e38f, vmax = -3.4e38f;
    for (int i = gid; i < n4; i += stride) {
        float4 v = x[i];
        vmin = fminf(vmin, fminf(fminf(v.x, v.y), fminf(v.z, v.w)));
        vmax = fmaxf(vmax, fmaxf(fmaxf(v.x, v.y), fmaxf(v.z, v.w)));
    }
    __shared__ float smin[256];
    __shared__ float smax[256];
    smin[tid] = vmin; smax[tid] = vmax;
    __syncthreads();
    for (int s = 128; s > 0; s >>= 1) {
        if (tid < s) {
            smin[tid] = fminf(smin[tid], smin[tid + s]);
            smax[tid] = fmaxf(smax[tid], smax[tid + s]);
        }
        __syncthreads();
    }
    if (tid == 0) {
        atomicMin(&mm[0], f2s(smin[0]));
        atomicMax(&mm[1], f2s(smax[0]));
    }
}

// Tile: 64 wide x 32 tall, halo 66 x 34. All FP math: f32, NO fma contraction,
// numpy-sequential op order (chaotic system: must track the np f32 trajectory).
// MODE 0: first step (s_in == 0, conv(s0,A)=0 exactly)
// MODE 1: middle step
// MODE 2: last step (apply (v+1)*0.5)
template <int MODE>
__global__ __launch_bounds__(256) void step_k(
    const float* __restrict__ x, const float* __restrict__ sin_,
    float* __restrict__ sout, const unsigned* __restrict__ mm,
    const float* __restrict__ wA, const float* __restrict__ wB,
    const float* __restrict__ biasp) {
#pragma clang fp contract(off)
    __shared__ float xs[34 * 66];
    __shared__ float ss[34 * 66];
    const int tid = threadIdx.x;
    const int col0 = blockIdx.x * 64;
    const int row0 = blockIdx.y * 32;
    const size_t img_off = (size_t)blockIdx.z * IMGPX;

    const float xmin = s2f(mm[0]);
    const float xmax = s2f(mm[1]);
    const float scale = 2.0f / (xmax - xmin);  // NEP50: f32 division
    const float b = biasp[0];
    float a[9], w[9];
#pragma unroll
    for (int i = 0; i < 9; ++i) {
        w[i] = wB[i];
        if (MODE != 0) a[i] = wA[i];
    }

    // halo-tile load; out-of-bounds = 0 (zero-pad in xn domain, matches conv pad)
    for (int i = tid; i < 34 * 66; i += 256) {
        const int r = i / 66;
        const int c = i - r * 66;
        const int gr = row0 + r - 1;
        const int gc = col0 + c - 1;
        const bool inb = (gr >= 0) & (gr < HW) & (gc >= 0) & (gc < HW);
        const size_t gidx = img_off + (size_t)gr * HW + gc;
        const float xv = inb ? x[gidx] : 0.0f;
        xs[i] = inb ? ((xv - xmin) * scale - 1.0f) : 0.0f;
        if (MODE != 0) ss[i] = inb ? sin_[gidx] : 0.0f;
    }
    __syncthreads();

    const int tx = tid & 63;
    const int ty = tid >> 6;
#pragma unroll
    for (int rr = 0; rr < 8; ++rr) {
        const int r = ty * 8 + rr;
        float accB = 0.0f;  // BU = conv(xn, B): sequential 9-term, kernel row-major
        float accA = 0.0f;  // conv(s, A): same order
#pragma unroll
        for (int dr = 0; dr < 3; ++dr) {
            const int base = (r + dr) * 66 + tx;
#pragma unroll
            for (int dc = 0; dc < 3; ++dc) {
                accB = accB + w[dr * 3 + dc] * xs[base + dc];
                if (MODE != 0) accA = accA + a[dr * 3 + dc] * ss[base + dc];
            }
        }
        // reference order: (conv(s,A) + bias) + BU   [step1: (0 + bias) + BU = b + BU]
        float v = (MODE == 0) ? (b + accB) : ((accA + b) + accB);
        v = fminf(fmaxf(v, -1.0f), 1.0f);  // np.clip
        if (MODE == 2) v = (v + 1.0f) * 0.5f;
        sout[img_off + (size_t)(row0 + r) * HW + col0 + tx] = v;
    }
}

extern "C" void kernel_launch(void* const* d_in, const int* in_sizes, int n_in,
                              void* d_out, int out_size, void* d_ws, size_t ws_size,
                              hipStream_t stream) {
    const float* x = (const float*)d_in[0];
    const float* wA = (const float*)d_in[1];
    const float* wB = (const float*)d_in[2];
    const float* bias = (const float*)d_in[3];
    float* out = (float*)d_out;
    unsigned* mm = (unsigned*)d_ws;
    float* pong = (float*)((char*)d_ws + 1024);  // 128 MiB f32 ping buffer

    mm_init<<<1, 1, 0, stream>>>(mm);
    mm_reduce<<<2048, 256, 0, stream>>>((const float4*)x, mm, (int)(NELEM / 4));

    dim3 grid(HW / 64, HW / 32, NIMG);
    // step1 -> out; even steps -> pong; odd -> out; step21 reads pong, writes out
    step_k<0><<<grid, 256, 0, stream>>>(x, nullptr, out, mm, wA, wB, bias);
    for (int t = 2; t <= 20; ++t) {
        const float* si = (t % 2 == 0) ? out : pong;
        float* so = (t % 2 == 0) ? pong : out;
        step_k<1><<<grid, 256, 0, stream>>>(x, si, so, mm, wA, wB, bias);
    }
    step_k<2><<<grid, 256, 0, stream>>>(x, pong, out, mm, wA, wB, bias);
}

// Round 5
// 1045.880 us; speedup vs baseline: 2.2339x; 2.2339x over previous
//
#include <hip/hip_runtime.h>

#define HW 1024
#define NIMG 32
#define IMGPX ((size_t)HW * HW)
#define NELEM (NIMG * IMGPX)

// Fused temporal blocking: 7 steps per kernel, 3 kernels = 21 steps.
// Compute region per block: 128x64 (fixed every step). Output tile: 116x52
// (region minus 6 contamination rings; k=7 steps -> 6 rings).
#define TOX 116
#define TOY 52
#define RW 128
#define RH 64
#define BROWS 66   // region rows -1..64
#define BCOLS 130  // region cols -1..128
#define BSTR 136   // LDS row stride in words; col c -> word c+4 (b128-aligned at c%4==0)
#define NBX 9      // ceil(1024/116)
#define NBY 20     // ceil(1024/52)

// ---- float <-> order-preserving unsigned (for atomic min/max) ----
__device__ __forceinline__ unsigned f2s(float f) {
    unsigned u = __float_as_uint(f);
    return (u & 0x80000000u) ? ~u : (u | 0x80000000u);
}
__device__ __forceinline__ float s2f(unsigned u) {
    return __uint_as_float((u & 0x80000000u) ? (u & 0x7fffffffu) : ~u);
}

__global__ void mm_init(unsigned* mm) {
    mm[0] = 0xFFFFFFFFu;
    mm[1] = 0u;
}

__global__ __launch_bounds__(256) void mm_reduce(const float4* __restrict__ x,
                                                 unsigned* mm, int n4) {
    const int tid = threadIdx.x;
    int gid = blockIdx.x * blockDim.x + tid;
    const int stride = gridDim.x * blockDim.x;
    float vmin = 3.4e38f, vmax = -3.4e38f;
    for (int i = gid; i < n4; i += stride) {
        float4 v = x[i];
        vmin = fminf(vmin, fminf(fminf(v.x, v.y), fminf(v.z, v.w)));
        vmax = fmaxf(vmax, fmaxf(fmaxf(v.x, v.y), fmaxf(v.z, v.w)));
    }
    __shared__ float smin[256];
    __shared__ float smax[256];
    smin[tid] = vmin; smax[tid] = vmax;
    __syncthreads();
    for (int s = 128; s > 0; s >>= 1) {
        if (tid < s) {
            smin[tid] = fminf(smin[tid], smin[tid + s]);
            smax[tid] = fmaxf(smax[tid], smax[tid + s]);
        }
        __syncthreads();
    }
    if (tid == 0) {
        atomicMin(&mm[0], f2s(smin[0]));
        atomicMax(&mm[1], f2s(smax[0]));
    }
}

// 6-value row load from LDS window: 1 b32 + 1 b128 + 1 b32
#define LOADROW(V, T)                                                     \
    do {                                                                  \
        const int _o = wbase + (T) * BSTR;                                \
        V[0] = sb[_o];                                                    \
        const float4 _q = *reinterpret_cast<const float4*>(&sb[_o + 1]);  \
        V[1] = _q.x; V[2] = _q.y; V[3] = _q.z; V[4] = _q.w;               \
        V[5] = sb[_o + 5];                                                \
    } while (0)

// one output row I (4 px) from window rows RA,RB,RC; 9-term sequential
// row-major accumulation (numpy order, NO fma)
#define CROW(RA, RB, RC, I, EPI)                                              \
    do {                                                                      \
        _Pragma("unroll") for (int j = 0; j < 4; ++j) {                       \
            float acc = 0.0f;                                                 \
            _Pragma("unroll") for (int dc = 0; dc < 3; ++dc)                  \
                acc = acc + cf[dc] * RA[j + dc];                              \
            _Pragma("unroll") for (int dc = 0; dc < 3; ++dc)                  \
                acc = acc + cf[3 + dc] * RB[j + dc];                          \
            _Pragma("unroll") for (int dc = 0; dc < 3; ++dc)                  \
                acc = acc + cf[6 + dc] * RC[j + dc];                          \
            EPI(I, j, acc);                                                   \
        }                                                                     \
    } while (0)

// 4x4 px block conv via 3-row sliding register window over 6 LDS rows
#define CONV4x4(EPI)                                      \
    do {                                                  \
        float w0_[6], w1_[6], w2_[6];                     \
        LOADROW(w0_, 0); LOADROW(w1_, 1);                 \
        { LOADROW(w2_, 2); CROW(w0_, w1_, w2_, 0, EPI); } \
        { LOADROW(w0_, 3); CROW(w1_, w2_, w0_, 1, EPI); } \
        { LOADROW(w1_, 4); CROW(w2_, w0_, w1_, 2, EPI); } \
        { LOADROW(w2_, 5); CROW(w0_, w1_, w2_, 3, EPI); } \
    } while (0)

#define EPI_BU(I, J, ACC) bu[I][J] = (ACC)
#define EPI_STEP(I, J, ACC)                              \
    do {                                                 \
        float v = ((ACC) + b) + bu[I][J];                \
        v = fminf(fmaxf(v, -1.0f), 1.0f);                \
        v = v * mR[I];                                   \
        v = v * mC[J];                                   \
        res[I][J] = v;                                   \
    } while (0)

template <int FIRST, int LAST>
__global__ __launch_bounds__(512) void fused_k(
    const float* __restrict__ x, const float* __restrict__ sin_,
    float* __restrict__ sout, const unsigned* __restrict__ mm,
    const float* __restrict__ wAp, const float* __restrict__ wBp,
    const float* __restrict__ biasp) {
#pragma clang fp contract(off)
    __shared__ float sb[BROWS * BSTR];
    const int tid = threadIdx.x;
    const int tx = tid & 31;   // col group: cols 4tx..4tx+3
    const int ty = tid >> 5;   // row group: rows 4ty..4ty+3
    const int ox = blockIdx.x * TOX - 6;  // region col c -> global ox + c
    const int oy = blockIdx.y * TOY - 6;  // region row r -> global oy + r
    const size_t img = (size_t)blockIdx.z * IMGPX;

    const float xmin = s2f(mm[0]);
    const float xmax = s2f(mm[1]);
    const float scale = 2.0f / (xmax - xmin);
    const float b = biasp[0];

    // ---- phase 1: xn tile into LDS ----
    for (int k = tid; k < BROWS * BCOLS; k += 512) {
        const int br = k / BCOLS;          // buffer row (region row br-1)
        const int cc = k - br * BCOLS;     // 0..129  (region col cc-1)
        const int gr = oy + br - 1;
        const int gc = ox + cc - 1;
        const bool inb = (gr >= 0) & (gr < HW) & (gc >= 0) & (gc < HW);
        float v = 0.0f;
        if (inb) v = (x[img + (size_t)gr * HW + gc] - xmin) * scale - 1.0f;
        sb[br * BSTR + cc + 3] = v;
    }
    __syncthreads();

    const int r0 = ty * 4;
    const int c0 = tx * 4;
    // window corner: region (r0-1, c0-1) -> buffer word r0*BSTR + c0+3
    const int wbase = r0 * BSTR + c0 + 3;

    // ---- phase 2: BU = conv(xn, B) into registers (time-invariant) ----
    float cf[9];
#pragma unroll
    for (int i = 0; i < 9; ++i) cf[i] = wBp[i];
    float bu[4][4];
    CONV4x4(EPI_BU);
    __syncthreads();

    // ---- phase 3: s tile into same LDS (zeros for first group) ----
    for (int k = tid; k < BROWS * BCOLS; k += 512) {
        const int br = k / BCOLS;
        const int cc = k - br * BCOLS;
        float v = 0.0f;
        if (!FIRST) {
            const int gr = oy + br - 1;
            const int gc = ox + cc - 1;
            const bool inb = (gr >= 0) & (gr < HW) & (gc >= 0) & (gc < HW);
            if (inb) v = sin_[img + (size_t)gr * HW + gc];
        }
        sb[br * BSTR + cc + 3] = v;
    }
    __syncthreads();

    // in-image masks (exact 0/1 multiply preserves zero-pad semantics)
    float mR[4], mC[4];
#pragma unroll
    for (int i = 0; i < 4; ++i) {
        const int g = oy + r0 + i;
        mR[i] = (g >= 0 && g < HW) ? 1.0f : 0.0f;
    }
#pragma unroll
    for (int j = 0; j < 4; ++j) {
        const int g = ox + c0 + j;
        mC[j] = (g >= 0 && g < HW) ? 1.0f : 0.0f;
    }

#pragma unroll
    for (int i = 0; i < 9; ++i) cf[i] = wAp[i];

    // ---- phase 4: 7 fused steps ----
    float res[4][4];
#pragma unroll 1
    for (int t = 0; t < 7; ++t) {
        CONV4x4(EPI_STEP);
        if (t < 6) {
            __syncthreads();
#pragma unroll
            for (int i = 0; i < 4; ++i) {
                const float4 q = make_float4(res[i][0], res[i][1], res[i][2], res[i][3]);
                *reinterpret_cast<float4*>(&sb[(r0 + i + 1) * BSTR + c0 + 4]) = q;
            }
            __syncthreads();
        }
    }

    // ---- phase 5: write output tile (inner 116x52 of region) ----
#pragma unroll
    for (int i = 0; i < 4; ++i) {
        const int r = r0 + i;
        const int gr = oy + r;
        if (r < 6 || r >= 6 + TOY || gr >= HW) continue;
#pragma unroll
        for (int j = 0; j < 4; ++j) {
            const int c = c0 + j;
            const int gc = ox + c;
            if (c < 6 || c >= 6 + TOX || gc >= HW) continue;
            float v = res[i][j];
            if (LAST) v = (v + 1.0f) * 0.5f;
            sout[img + (size_t)gr * HW + gc] = v;
        }
    }
}

extern "C" void kernel_launch(void* const* d_in, const int* in_sizes, int n_in,
                              void* d_out, int out_size, void* d_ws, size_t ws_size,
                              hipStream_t stream) {
    const float* x = (const float*)d_in[0];
    const float* wA = (const float*)d_in[1];
    const float* wB = (const float*)d_in[2];
    const float* bias = (const float*)d_in[3];
    float* out = (float*)d_out;
    unsigned* mm = (unsigned*)d_ws;
    float* pong = (float*)((char*)d_ws + 1024);  // 128 MiB f32 buffer

    mm_init<<<1, 1, 0, stream>>>(mm);
    mm_reduce<<<2048, 256, 0, stream>>>((const float4*)x, mm, (int)(NELEM / 4));

    dim3 grid(NBX, NBY, NIMG);
    // steps 1-7: zeros -> d_out (scratch); 8-14: d_out -> pong; 15-21: pong -> d_out
    fused_k<1, 0><<<grid, 512, 0, stream>>>(x, nullptr, out, mm, wA, wB, bias);
    fused_k<0, 0><<<grid, 512, 0, stream>>>(x, out, pong, mm, wA, wB, bias);
    fused_k<0, 1><<<grid, 512, 0, stream>>>(x, pong, out, mm, wA, wB, bias);
}